// Round 1
// baseline (1933.708 us; speedup 1.0000x reference)
//
#include <hip/hip_runtime.h>
#include <math.h>

#define HID 50
#define NG 200     // 4*HID
#define TT 512
#define HP 52      // h padded to multiple of 4

// One block = one batch element. 256 threads:
//   threads 0..199: gate threads (gate g = tid), W_hh row in registers
//   update role: wave w, lanes 0..12 -> unit u = 13*w + lane (u < 50)
__global__ __launch_bounds__(256, 4) void lstm_fp32_kernel(
    const float* __restrict__ x,      // [B, T]
    const float* __restrict__ W_ih,   // [200, 1]
    const float* __restrict__ W_hh,   // [200, 50]
    const float* __restrict__ b_ih,   // [200]
    const float* __restrict__ b_hh,   // [200]
    const float* __restrict__ W_out,  // [1, 50]
    const float* __restrict__ b_out,  // [1]
    float* __restrict__ out)          // [B, T]
{
    const int b    = blockIdx.x;
    const int tid  = threadIdx.x;
    const int wave = tid >> 6;
    const int lane = tid & 63;

    __shared__ __align__(16) float h_lds[HP];
    __shared__ float ag[NG];
    __shared__ float xbuf[TT];
    __shared__ float yred[4];

    // stage x[b, :] into LDS (coalesced)
    const float* xb = x + (size_t)b * TT;
    for (int i = tid; i < TT; i += 256) xbuf[i] = xb[i];

    // gate-thread weights in registers
    const int g = tid;                 // gate id, active if < 200
    float w[HP];
    float wih = 0.f, bias = 0.f;
    if (g < NG) {
        #pragma unroll
        for (int k = 0; k < HID; ++k) w[k] = W_hh[g * HID + k];
        w[50] = 0.f; w[51] = 0.f;
        wih  = W_ih[g];
        bias = b_ih[g] + b_hh[g];
    } else {
        #pragma unroll
        for (int k = 0; k < HP; ++k) w[k] = 0.f;
    }
    const bool is_tanh_gate = (g >= 100) && (g < 150);

    // update-thread state
    const int u = wave * 13 + lane;
    const bool upd = (lane < 13) && (u < HID);
    float c = 0.f, wout = 0.f;
    if (upd) wout = W_out[u];
    const float bo = b_out[0];

    // init h = 0 (pads stay 0 forever)
    if (tid < HP) h_lds[tid] = 0.f;
    __syncthreads();

    float* yout = out + (size_t)b * TT;

    for (int t = 0; t < TT; ++t) {
        // ---- gate phase: acc = x_t*wih + bias + sum_k W_hh[g][k]*h[k] ----
        const float xt = xbuf[t];
        float a0 = fmaf(wih, xt, bias);
        float a1 = 0.f, a2 = 0.f, a3 = 0.f;
        #pragma unroll
        for (int k4 = 0; k4 < HP / 4; ++k4) {
            float4 v = ((const float4*)h_lds)[k4];   // broadcast read
            a0 = fmaf(w[4 * k4 + 0], v.x, a0);
            a1 = fmaf(w[4 * k4 + 1], v.y, a1);
            a2 = fmaf(w[4 * k4 + 2], v.z, a2);
            a3 = fmaf(w[4 * k4 + 3], v.w, a3);
        }
        float acc = (a0 + a1) + (a2 + a3);

        // activation: sigmoid for i,f,o; tanh(z) = 2*sigmoid(2z)-1 for g
        float z = is_tanh_gate ? 2.f * acc : acc;
        float s = __builtin_amdgcn_rcpf(1.f + __expf(-z));
        float a = is_tanh_gate ? fmaf(2.f, s, -1.f) : s;
        if (g < NG) ag[g] = a;
        __syncthreads();   // B1: ag ready; all h reads done

        // ---- update phase: c,h for this wave's units ----
        float p = 0.f;
        if (upd) {
            float gi = ag[u];
            float gf = ag[u + 50];
            float gg = ag[u + 100];
            float go = ag[u + 150];
            c = fmaf(gf, c, gi * gg);
            float s2 = __builtin_amdgcn_rcpf(1.f + __expf(-2.f * c));
            float tc = fmaf(2.f, s2, -1.f);
            float h = go * tc;
            h_lds[u] = h;
            p = h * wout;
        }
        // reduce p over 16-lane groups (active lanes 0..12, rest are 0)
        p += __shfl_down(p, 8, 16);
        p += __shfl_down(p, 4, 16);
        p += __shfl_down(p, 2, 16);
        p += __shfl_down(p, 1, 16);
        if (lane == 0) yred[wave] = p;
        __syncthreads();   // B2: h_lds + yred ready

        if (tid == 0) {
            yout[t] = ((yred[0] + yred[1]) + (yred[2] + yred[3])) + bo;
        }
    }
}

extern "C" void kernel_launch(void* const* d_in, const int* in_sizes, int n_in,
                              void* d_out, int out_size, void* d_ws, size_t ws_size,
                              hipStream_t stream) {
    const float* x     = (const float*)d_in[0];
    const float* W_ih  = (const float*)d_in[1];
    const float* W_hh  = (const float*)d_in[2];
    const float* b_ih  = (const float*)d_in[3];
    const float* b_hh  = (const float*)d_in[4];
    const float* W_out = (const float*)d_in[5];
    const float* b_out = (const float*)d_in[6];
    float* out = (float*)d_out;

    const int B = in_sizes[0] / TT;   // 4096
    lstm_fp32_kernel<<<B, 256, 0, stream>>>(x, W_ih, W_hh, b_ih, b_hh,
                                            W_out, b_out, out);
}

// Round 3
// 998.350 us; speedup vs baseline: 1.9369x; 1.9369x over previous
//
#include <hip/hip_runtime.h>
#include <math.h>

#define HID 50
#define TT 512

typedef float v2f __attribute__((ext_vector_type(2)));

__device__ __forceinline__ float sigmoid_fast(float x) {
    // 1 / (1 + 2^(-x*log2e))
    return __builtin_amdgcn_rcpf(1.f + __builtin_amdgcn_exp2f(-1.44269504088896f * x));
}
__device__ __forceinline__ float tanh_fast(float x) {
    // 2*sigmoid(2x) - 1
    return fmaf(2.f, __builtin_amdgcn_rcpf(1.f + __builtin_amdgcn_exp2f(-2.88539008177793f * x)), -1.f);
}

// float-valued lane broadcast (readlane builtin is int-typed -- MUST bitcast,
// implicit conversion silently truncates the VALUE; that was R1's bug)
__device__ __forceinline__ float bcast_lane(float v, int k) {
    return __int_as_float(__builtin_amdgcn_readlane(__float_as_int(v), k));
}

// One wave (64 threads) per batch element. Lane u (<50) owns hidden unit u:
// holds rows u, u+50, u+100, u+150 of W_hh in VGPRs, computes gates i,f,g,o
// for unit u each step. h_u stays in lane u's register; the matvec broadcast
// of h is done with v_readlane (VALU/SALU) -- zero LDS traffic in the matvec.
__global__ __launch_bounds__(64, 2) void lstm_wave_kernel(
    const float* __restrict__ x,      // [B, T]
    const float* __restrict__ W_ih,   // [200, 1]
    const float* __restrict__ W_hh,   // [200, 50]
    const float* __restrict__ b_ih,   // [200]
    const float* __restrict__ b_hh,   // [200]
    const float* __restrict__ W_out,  // [1, 50]
    const float* __restrict__ b_out,  // [1]
    float* __restrict__ out)          // [B, T]
{
    const int b    = blockIdx.x;
    const int lane = threadIdx.x;            // 0..63

    __shared__ __align__(16) float xbuf[TT];

    // stage x[b,:] (coalesced float4)
    const float4* xb4 = (const float4*)(x + (size_t)b * TT);
    #pragma unroll
    for (int i = 0; i < TT / 4 / 64; ++i)    // 2 iters
        ((float4*)xbuf)[i * 64 + lane] = xb4[i * 64 + lane];
    __syncthreads();

    const int u = (lane < HID) ? lane : 0;   // lanes >=50 mirror unit 0 (masked via wout=0)
    // per-lane weights: (i,f) and (g,o) packed as float2 for v_pk_fma_f32
    v2f w_if[HID], w_go[HID];
    #pragma unroll
    for (int k = 0; k < HID; ++k) {
        w_if[k] = (v2f){ W_hh[(u       ) * HID + k], W_hh[(u +  50) * HID + k] };
        w_go[k] = (v2f){ W_hh[(u + 100) * HID + k], W_hh[(u + 150) * HID + k] };
    }
    const v2f wih_if = (v2f){ W_ih[u],       W_ih[u + 50] };
    const v2f wih_go = (v2f){ W_ih[u + 100], W_ih[u + 150] };
    const v2f bia_if = (v2f){ b_ih[u]       + b_hh[u],       b_ih[u + 50]  + b_hh[u + 50]  };
    const v2f bia_go = (v2f){ b_ih[u + 100] + b_hh[u + 100], b_ih[u + 150] + b_hh[u + 150] };
    const float wout = (lane < HID) ? W_out[u] : 0.f;
    const float bo   = b_out[0];

    float h = 0.f, c = 0.f;
    float ybuf = 0.f;                        // coalesced-store staging
    float* yout = out + (size_t)b * TT;

    for (int t = 0; t < TT; ++t) {
        const float xt = xbuf[t];            // broadcast ds_read_b32, 1/step
        // two accumulator chains (even/odd k) per gate pair: chain length 25,
        // matches R0's rounding behavior (R0 passed at 4.9e-4)
        v2f e_if, e_go, o_if = (v2f){0.f, 0.f}, o_go = (v2f){0.f, 0.f};
        e_if.x = fmaf(wih_if.x, xt, bia_if.x);
        e_if.y = fmaf(wih_if.y, xt, bia_if.y);
        e_go.x = fmaf(wih_go.x, xt, bia_go.x);
        e_go.y = fmaf(wih_go.y, xt, bia_go.y);

        #pragma unroll
        for (int k = 0; k < HID; k += 2) {
            const float h0 = bcast_lane(h, k);
            const float h1 = bcast_lane(h, k + 1);
            e_if.x = fmaf(w_if[k].x, h0, e_if.x);
            e_if.y = fmaf(w_if[k].y, h0, e_if.y);
            e_go.x = fmaf(w_go[k].x, h0, e_go.x);
            e_go.y = fmaf(w_go[k].y, h0, e_go.y);
            o_if.x = fmaf(w_if[k + 1].x, h1, o_if.x);
            o_if.y = fmaf(w_if[k + 1].y, h1, o_if.y);
            o_go.x = fmaf(w_go[k + 1].x, h1, o_go.x);
            o_go.y = fmaf(w_go[k + 1].y, h1, o_go.y);
        }
        const float acc_i = e_if.x + o_if.x;
        const float acc_f = e_if.y + o_if.y;
        const float acc_g = e_go.x + o_go.x;
        const float acc_o = e_go.y + o_go.y;

        const float gi = sigmoid_fast(acc_i);
        const float gf = sigmoid_fast(acc_f);
        const float gg = tanh_fast(acc_g);
        const float go = sigmoid_fast(acc_o);
        c = fmaf(gf, c, gi * gg);
        h = go * tanh_fast(c);

        // y_t = sum_u wout_u * h_u + bo   (butterfly -> all lanes hold sum)
        float p = h * wout;
        p += __shfl_xor(p, 1);
        p += __shfl_xor(p, 2);
        p += __shfl_xor(p, 4);
        p += __shfl_xor(p, 8);
        p += __shfl_xor(p, 16);
        p += __shfl_xor(p, 32);
        if (lane == (t & 63)) ybuf = p + bo;
        if ((t & 63) == 63)                  // coalesced store every 64 steps
            yout[(t & ~63) + lane] = ybuf;
    }
}

extern "C" void kernel_launch(void* const* d_in, const int* in_sizes, int n_in,
                              void* d_out, int out_size, void* d_ws, size_t ws_size,
                              hipStream_t stream) {
    const float* x     = (const float*)d_in[0];
    const float* W_ih  = (const float*)d_in[1];
    const float* W_hh  = (const float*)d_in[2];
    const float* b_ih  = (const float*)d_in[3];
    const float* b_hh  = (const float*)d_in[4];
    const float* W_out = (const float*)d_in[5];
    const float* b_out = (const float*)d_in[6];
    float* out = (float*)d_out;

    const int B = in_sizes[0] / TT;          // 4096
    lstm_wave_kernel<<<B, 64, 0, stream>>>(x, W_ih, W_hh, b_ih, b_hh,
                                           W_out, b_out, out);
}

// Round 4
// 579.033 us; speedup vs baseline: 3.3395x; 1.7242x over previous
//
#include <hip/hip_runtime.h>
#include <math.h>

#define HID 50
#define TT  512
#define BT  16           // batch elements per block
#define GS_STRIDE 260    // Gs row stride in floats (256 + pad; 1040B rows, 16B aligned, <=2-way banks)
#define HS_STRIDE 72     // H plane row stride in bf16 (64 + pad; 144B rows, 16B aligned)

typedef __attribute__((ext_vector_type(8))) short bf16x8;
typedef __attribute__((ext_vector_type(4))) float f32x4;

__device__ __forceinline__ float sigmoid_fast(float x) {
    return __builtin_amdgcn_rcpf(1.f + __builtin_amdgcn_exp2f(-1.44269504088896f * x));
}
__device__ __forceinline__ float tanh_fast(float x) {
    return fmaf(2.f, __builtin_amdgcn_rcpf(1.f + __builtin_amdgcn_exp2f(-2.88539008177793f * x)), -1.f);
}
__device__ __forceinline__ short bf16_rtne(float f) {
    unsigned u = __float_as_uint(f);
    u = (u + 0x7FFFu + ((u >> 16) & 1u)) >> 16;
    return (short)u;
}
__device__ __forceinline__ float bf16_f32(short s) {
    return __uint_as_float(((unsigned)(unsigned short)s) << 16);
}

// Block = 256 threads (4 waves) handles BT=16 batch elements for all T.
// Per step: G[256 gate-rows x 16 b] = W~[256 x 64] * H[64 x 16] via
// mfma_f32_16x16x32_bf16, split-precision (hi/lo bf16, lo*lo dropped).
// Gate-row permutation: row g^ = u*4 + type (type: 0=i,1=f,2=g,3=o), so the
// 4 gates of unit u are contiguous -> b128 LDS writes AND reads.
// K-slots: 0..49 = W_hh cols (h), 50 = W_ih (x_t), 51 = bias (1.0), 52..63 = 0.
__global__ __launch_bounds__(256) void lstm_mfma_kernel(
    const float* __restrict__ x,      // [B, T]
    const float* __restrict__ W_ih,   // [200, 1]
    const float* __restrict__ W_hh,   // [200, 50]
    const float* __restrict__ b_ih,   // [200]
    const float* __restrict__ b_hh,   // [200]
    const float* __restrict__ W_out,  // [1, 50]
    const float* __restrict__ b_out,  // [1]
    float* __restrict__ out)          // [B, T]
{
    const int tid  = threadIdx.x;
    const int lane = tid & 63;
    const int wave = tid >> 6;
    const int col  = lane & 15;      // MFMA: A-row-in-tile / B-col(batch) / D-col(batch)
    const int quad = lane >> 4;      // MFMA: k-group / D row-group

    __shared__ __align__(16) float          Gs[BT][GS_STRIDE];
    __shared__ __align__(16) unsigned short Hhi[BT][HS_STRIDE];
    __shared__ __align__(16) unsigned short Hlo[BT][HS_STRIDE];

    // ---- zero H planes (pad k-slots 52..63 must be 0; rest overwritten) ----
    for (int i = tid; i < BT * HS_STRIDE; i += 256) {
        (&Hhi[0][0])[i] = 0;
        (&Hlo[0][0])[i] = 0;
    }
    __syncthreads();

    // ---- persistent A fragments: W~ hi/lo, permuted rows, K-folded x/bias ----
    // wave w owns g^ rows [w*64, w*64+64) = 4 M-tiles.
    bf16x8 Ahi[4][2], Alo[4][2];
    #pragma unroll
    for (int i = 0; i < 4; ++i) {
        const int gh  = wave * 64 + i * 16 + col;   // g^ row
        const int u   = gh >> 2;
        const int ty  = gh & 3;
        const bool vl = (u < HID);
        const int og  = ty * HID + u;               // original gate row (i,f,g,o blocks)
        #pragma unroll
        for (int kk = 0; kk < 2; ++kk) {
            #pragma unroll
            for (int j = 0; j < 8; ++j) {
                const int k = kk * 32 + quad * 8 + j;
                float v = 0.f;
                if (vl) {
                    if (k < HID)       v = W_hh[og * HID + k];
                    else if (k == 50)  v = W_ih[og];
                    else if (k == 51)  v = b_ih[og] + b_hh[og];
                }
                const short hi = bf16_rtne(v);
                const short lo = bf16_rtne(v - bf16_f32(hi));
                Ahi[i][kk][j] = hi;
                Alo[i][kk][j] = lo;
            }
        }
    }

    // ---- update-phase constants & state ----
    const int b  = tid >> 4;         // local batch owned in update phase
    const int ub = tid & 15;         // unit base; units u = ub + 16*s
    float c[4] = {0.f, 0.f, 0.f, 0.f};
    float wo[4];
    #pragma unroll
    for (int s = 0; s < 4; ++s) {
        const int u = ub + 16 * s;
        wo[s] = (u < HID) ? W_out[u] : 0.f;
    }
    const float bo = b_out[0];
    const float* xrow = x + (size_t)(blockIdx.x * BT + tid) * TT; // valid when tid < BT

    // x slot (k=50) for t=0, bias slot (k=51) = 1.0 (constant forever)
    if (tid < BT) {
        Hhi[tid][51] = 0x3F80;       // bf16(1.0)
        const float x0 = xrow[0];
        const short hi = bf16_rtne(x0);
        Hhi[tid][50] = (unsigned short)hi;
        Hlo[tid][50] = (unsigned short)bf16_rtne(x0 - bf16_f32(hi));
    }
    __syncthreads();

    float* yout = out + (size_t)(blockIdx.x * BT) * TT;

    for (int t = 0; t < TT; ++t) {
        // ======== MFMA phase: G = W~ * H ========
        bf16x8 Bh[2], Bl[2];
        #pragma unroll
        for (int kk = 0; kk < 2; ++kk) {
            Bh[kk] = *(const bf16x8*)&Hhi[col][kk * 32 + quad * 8];
            Bl[kk] = *(const bf16x8*)&Hlo[col][kk * 32 + quad * 8];
        }
        #pragma unroll
        for (int i = 0; i < 4; ++i) {
            f32x4 acc = {0.f, 0.f, 0.f, 0.f};
            #pragma unroll
            for (int kk = 0; kk < 2; ++kk) {
                acc = __builtin_amdgcn_mfma_f32_16x16x32_bf16(Ahi[i][kk], Bh[kk], acc, 0, 0, 0);
                acc = __builtin_amdgcn_mfma_f32_16x16x32_bf16(Ahi[i][kk], Bl[kk], acc, 0, 0, 0);
                acc = __builtin_amdgcn_mfma_f32_16x16x32_bf16(Alo[i][kk], Bh[kk], acc, 0, 0, 0);
            }
            // D: row g^ = wave*64 + i*16 + quad*4 + reg, col b = col -> Gs[b][g^] b128
            *(f32x4*)&Gs[col][wave * 64 + i * 16 + quad * 4] = acc;
        }
        __syncthreads();

        // ======== update phase ========
        float xn = 0.f;
        if (tid < BT) xn = xrow[(t + 1 < TT) ? (t + 1) : t];   // prefetch next x
        float p = 0.f;
        #pragma unroll
        for (int s = 0; s < 4; ++s) {
            const int u = ub + 16 * s;                  // 0..63 (>=50 are phantoms, zero wt)
            const f32x4 g4 = *(const f32x4*)&Gs[b][u * 4];  // {i,f,g,o} preacts, complete
            const float gi = sigmoid_fast(g4.x);
            const float gf = sigmoid_fast(g4.y);
            const float gg = tanh_fast(g4.z);
            const float go = sigmoid_fast(g4.w);
            c[s] = fmaf(gf, c[s], gi * gg);
            const float h = go * tanh_fast(c[s]);
            if (u < HID) {                               // don't clobber k-slots 50/51
                const short hh = bf16_rtne(h);
                Hhi[b][u] = (unsigned short)hh;
                Hlo[b][u] = (unsigned short)bf16_rtne(h - bf16_f32(hh));
            }
            p = fmaf(h, wo[s], p);                       // phantom wo = 0
        }
        // y_b = sum over the 16 threads sharing b (they are one 16-lane group)
        p += __shfl_xor(p, 1);
        p += __shfl_xor(p, 2);
        p += __shfl_xor(p, 4);
        p += __shfl_xor(p, 8);
        if (ub == 0) yout[(size_t)b * TT + t] = p + bo;
        // x slot for next step
        if (tid < BT) {
            const short hi = bf16_rtne(xn);
            Hhi[tid][50] = (unsigned short)hi;
            Hlo[tid][50] = (unsigned short)bf16_rtne(xn - bf16_f32(hi));
        }
        __syncthreads();
    }
}

extern "C" void kernel_launch(void* const* d_in, const int* in_sizes, int n_in,
                              void* d_out, int out_size, void* d_ws, size_t ws_size,
                              hipStream_t stream) {
    const float* x     = (const float*)d_in[0];
    const float* W_ih  = (const float*)d_in[1];
    const float* W_hh  = (const float*)d_in[2];
    const float* b_ih  = (const float*)d_in[3];
    const float* b_hh  = (const float*)d_in[4];
    const float* W_out = (const float*)d_in[5];
    const float* b_out = (const float*)d_in[6];
    float* out = (float*)d_out;

    const int B = in_sizes[0] / TT;          // 4096
    lstm_mfma_kernel<<<B / BT, 256, 0, stream>>>(x, W_ih, W_hh, b_ih, b_hh,
                                                 W_out, b_out, out);
}

// Round 5
// 420.867 us; speedup vs baseline: 4.5946x; 1.3758x over previous
//
#include <hip/hip_runtime.h>
#include <math.h>

#define HID 50
#define TT  512
#define BT  16      // batch per block
#define NW  8       // waves per block
#define HS  72      // H plane row stride (shorts): 144B ≡ 16 mod 128 -> 4-bank row shift
#define XS  513     // x_lds row stride (floats): bank shift 1/row -> conflict-free column read

typedef __attribute__((ext_vector_type(8))) short bf16x8;
typedef __attribute__((ext_vector_type(4))) float f32x4;

__device__ __forceinline__ float sigmoid_fast(float x) {
    return __builtin_amdgcn_rcpf(1.f + __builtin_amdgcn_exp2f(-1.44269504088896f * x));
}
__device__ __forceinline__ float tanh_fast(float x) {
    return fmaf(2.f, __builtin_amdgcn_rcpf(1.f + __builtin_amdgcn_exp2f(-2.88539008177793f * x)), -1.f);
}
__device__ __forceinline__ short bf16_rtne(float f) {
    unsigned u = __float_as_uint(f);
    u = (u + 0x7FFFu + ((u >> 16) & 1u)) >> 16;
    return (short)u;
}
__device__ __forceinline__ float bf16_f32(short s) {
    return __uint_as_float(((unsigned)(unsigned short)s) << 16);
}

// Block = 512 threads (8 waves), BT=16 batch for all T. Per step ONE barrier:
//   G[256 x 16] = W~[256 x 64] * H[64 x 16] via mfma_f32_16x16x32_bf16 split-bf16.
// Row permutation g^ = u*4 + ty makes the D-fragment of lane (col,quad) hold
// ALL FOUR gate preacts of unit u = wv*8 + i*4 + quad for batch col -- so the
// activation runs directly on acc registers (no Gs LDS round-trip, R3's
// 2.33e7-conflict hotspot). H planes and ypart are double-buffered so the
// WAR hazard needs no second barrier.
__global__ __launch_bounds__(512) void lstm_mfma2_kernel(
    const float* __restrict__ x,      // [B, T]
    const float* __restrict__ W_ih,   // [200, 1]
    const float* __restrict__ W_hh,   // [200, 50]
    const float* __restrict__ b_ih,   // [200]
    const float* __restrict__ b_hh,   // [200]
    const float* __restrict__ W_out,  // [1, 50]
    const float* __restrict__ b_out,  // [1]
    float* __restrict__ out)          // [B, T]
{
    const int tid  = threadIdx.x;
    const int lane = tid & 63;
    const int wv   = tid >> 6;       // 0..7
    const int col  = lane & 15;      // A-row-in-tile / B-col(batch) / D-col(batch)
    const int quad = lane >> 4;      // k-octet / D row-group

    __shared__ __align__(16) unsigned short Hhi[2][BT][HS];
    __shared__ __align__(16) unsigned short Hlo[2][BT][HS];
    __shared__ float x_lds[BT][XS];
    __shared__ float ypart[2][NW][17];

    // zero both H buffers (pad k-slots 52..63 must stay 0)
    for (int i = tid; i < 2 * BT * HS; i += 512) {
        (&Hhi[0][0][0])[i] = 0;
        (&Hlo[0][0][0])[i] = 0;
    }
    // stage x[block,:,:] -> LDS (coalesced float4 reads)
    {
        const float4* xg = (const float4*)(x + (size_t)blockIdx.x * BT * TT);
        #pragma unroll
        for (int pk = 0; pk < (BT * TT / 4) / 512; ++pk) {   // 4 iters
            const int idx = pk * 512 + tid;                  // float4 index
            const float4 v = xg[idx];
            const int fb = (idx * 4) >> 9;
            const int ft = (idx * 4) & 511;
            x_lds[fb][ft + 0] = v.x; x_lds[fb][ft + 1] = v.y;
            x_lds[fb][ft + 2] = v.z; x_lds[fb][ft + 3] = v.w;
        }
    }

    // persistent A fragments: wave wv owns g^ rows [wv*32, wv*32+32) = 2 tiles
    // K-slots: 0..49 = W_hh cols, 50 = W_ih (x), 51 = bias (B slot = 1.0), 52..63 = 0
    bf16x8 Ahi[2][2], Alo[2][2];
    #pragma unroll
    for (int i = 0; i < 2; ++i) {
        const int gh  = wv * 32 + i * 16 + col;   // g^ row
        const int u   = gh >> 2;
        const int ty  = gh & 3;
        const bool vl = (u < HID);
        const int og  = ty * HID + u;             // original gate row
        #pragma unroll
        for (int kk = 0; kk < 2; ++kk) {
            #pragma unroll
            for (int j = 0; j < 8; ++j) {
                const int k = kk * 32 + quad * 8 + j;
                float v = 0.f;
                if (vl) {
                    if (k < HID)       v = W_hh[og * HID + k];
                    else if (k == 50)  v = W_ih[og];
                    else if (k == 51)  v = b_ih[og] + b_hh[og];
                }
                const short hi = bf16_rtne(v);
                Ahi[i][kk][j] = hi;
                Alo[i][kk][j] = bf16_rtne(v - bf16_f32(hi));
            }
        }
    }

    // act-phase constants & state: lane owns units u_i = wv*8 + i*4 + quad, batch=col
    float c[2] = {0.f, 0.f};
    float wo[2];
    #pragma unroll
    for (int i = 0; i < 2; ++i) {
        const int u = wv * 8 + i * 4 + quad;
        wo[i] = (u < HID) ? W_out[u] : 0.f;
    }
    const float bo = b_out[0];
    float* yout = out + (size_t)blockIdx.x * BT * TT;

    __syncthreads();    // x_lds + zeroed H visible

    if (tid < BT) {     // bias slot (both buffers, constant), x_0 slot (buffer 0)
        Hhi[0][tid][51] = 0x3F80;
        Hhi[1][tid][51] = 0x3F80;
        const float x0 = x_lds[tid][0];
        const short h0 = bf16_rtne(x0);
        Hhi[0][tid][50] = (unsigned short)h0;
        Hlo[0][tid][50] = (unsigned short)bf16_rtne(x0 - bf16_f32(h0));
    }
    __syncthreads();

    for (int t = 0; t < TT; ++t) {
        const int p = t & 1;        // read buffer; write 1-p

        // y_{t-1}: partials written before last barrier; store issued EARLY so
        // its vmcnt retires under this step's compute (no drain at the barrier)
        if (t > 0 && tid < BT) {
            float s = bo;
            #pragma unroll
            for (int w = 0; w < NW; ++w) s += ypart[1 - p][w][tid];
            yout[(size_t)tid * TT + (t - 1)] = s;
        }

        // B fragments (hi/lo), layout B[k=quad*8+j+kk*32][n=col]
        bf16x8 Bh[2], Bl[2];
        #pragma unroll
        for (int kk = 0; kk < 2; ++kk) {
            Bh[kk] = *(const bf16x8*)&Hhi[p][col][kk * 32 + quad * 8];
            Bl[kk] = *(const bf16x8*)&Hlo[p][col][kk * 32 + quad * 8];
        }

        float psum = 0.f;
        #pragma unroll
        for (int i = 0; i < 2; ++i) {
            f32x4 acc = {0.f, 0.f, 0.f, 0.f};
            #pragma unroll
            for (int kk = 0; kk < 2; ++kk) {
                acc = __builtin_amdgcn_mfma_f32_16x16x32_bf16(Ahi[i][kk], Bh[kk], acc, 0, 0, 0);
                acc = __builtin_amdgcn_mfma_f32_16x16x32_bf16(Ahi[i][kk], Bl[kk], acc, 0, 0, 0);
                acc = __builtin_amdgcn_mfma_f32_16x16x32_bf16(Alo[i][kk], Bh[kk], acc, 0, 0, 0);
            }
            // acc = {pre_i, pre_f, pre_g, pre_o} of unit u, batch col
            const int u = wv * 8 + i * 4 + quad;
            const float gi = sigmoid_fast(acc.x);
            const float gf = sigmoid_fast(acc.y);
            const float gg = tanh_fast(acc.z);
            const float go = sigmoid_fast(acc.w);
            c[i] = fmaf(gf, c[i], gi * gg);
            const float h = go * tanh_fast(c[i]);
            if (u < HID) {           // don't clobber x/bias/zero k-slots
                const short hh = bf16_rtne(h);
                Hhi[1 - p][col][u] = (unsigned short)hh;
                Hlo[1 - p][col][u] = (unsigned short)bf16_rtne(h - bf16_f32(hh));
            }
            psum = fmaf(h, wo[i], psum);   // phantom wo = 0
        }

        // x_{t+1} into the write buffer (conflict-free column read of x_lds)
        if (tid < BT) {
            const float xn = x_lds[tid][(t + 1 < TT) ? t + 1 : t];
            const short hx = bf16_rtne(xn);
            Hhi[1 - p][tid][50] = (unsigned short)hx;
            Hlo[1 - p][tid][50] = (unsigned short)bf16_rtne(xn - bf16_f32(hx));
        }

        // per-wave y partial: sum over quad groups (lanes col, col+16, col+32, col+48)
        psum += __shfl_xor(psum, 16);
        psum += __shfl_xor(psum, 32);
        if (lane < 16) ypart[p][wv][col] = psum;

        __syncthreads();    // the ONE barrier: h/x/ypart visible for step t+1
    }

    // epilogue: y_{TT-1}
    if (tid < BT) {
        float s = bo;
        #pragma unroll
        for (int w = 0; w < NW; ++w) s += ypart[(TT - 1) & 1][w][tid];
        yout[(size_t)tid * TT + (TT - 1)] = s;
    }
}

extern "C" void kernel_launch(void* const* d_in, const int* in_sizes, int n_in,
                              void* d_out, int out_size, void* d_ws, size_t ws_size,
                              hipStream_t stream) {
    const float* x     = (const float*)d_in[0];
    const float* W_ih  = (const float*)d_in[1];
    const float* W_hh  = (const float*)d_in[2];
    const float* b_ih  = (const float*)d_in[3];
    const float* b_hh  = (const float*)d_in[4];
    const float* W_out = (const float*)d_in[5];
    const float* b_out = (const float*)d_in[6];
    float* out = (float*)d_out;

    const int B = in_sizes[0] / TT;          // 4096
    lstm_mfma2_kernel<<<B / BT, 512, 0, stream>>>(x, W_ih, W_hh, b_ih, b_hh,
                                                  W_out, b_out, out);
}

// Round 6
// 358.498 us; speedup vs baseline: 5.3939x; 1.1740x over previous
//
#include <hip/hip_runtime.h>
#include <math.h>

#define HID 50
#define TT  512
#define BT  16      // batch per block
#define NW  8       // waves per block
#define HS  72      // H plane row stride in shorts (144B: 16B-aligned rows, 4-bank row shift)
#define XS  513     // x_lds row stride (floats): +1 bank/row -> conflict-free column read

typedef __attribute__((ext_vector_type(8))) short bf16x8;
typedef __attribute__((ext_vector_type(4))) float f32x4;

__device__ __forceinline__ float sigmoid_fast(float x) {
    return __builtin_amdgcn_rcpf(1.f + __builtin_amdgcn_exp2f(-1.44269504088896f * x));
}
__device__ __forceinline__ float tanh_fast(float x) {
    return fmaf(2.f, __builtin_amdgcn_rcpf(1.f + __builtin_amdgcn_exp2f(-2.88539008177793f * x)), -1.f);
}
__device__ __forceinline__ short bf16_rtne(float f) {
    unsigned u = __float_as_uint(f);
    u = (u + 0x7FFFu + ((u >> 16) & 1u)) >> 16;
    return (short)u;
}
__device__ __forceinline__ float bf16_f32(short s) {
    return __uint_as_float(((unsigned)(unsigned short)s) << 16);
}

// Block = 512 threads (8 waves), BT=16 batch, ONE barrier/step.
// G[256 x 16] = W~[256 x 64] * H[64 x 16], mfma_f32_16x16x32_bf16.
// Precision scheme: A (weights/bias) split hi+lo bf16 (2 MFMAs); H plane is
// SINGLE bf16 (h quantization ~2^-9 relative, contracted by forget gate);
// x keeps full precision via two K-slots (50=x_hi, 52=x_lo) with W_ih
// duplicated in both A columns. Row permutation g^ = u*4+ty puts all 4 gate
// preacts of unit u in one lane's D fragment (no G round-trip).
// K-slots: 0..49 = W_hh cols, 50 = x_hi, 51 = bias (B=1.0), 52 = x_lo, 53..63 = 0.
__global__ __launch_bounds__(512) void lstm_mfma3_kernel(
    const float* __restrict__ x,      // [B, T]
    const float* __restrict__ W_ih,   // [200, 1]
    const float* __restrict__ W_hh,   // [200, 50]
    const float* __restrict__ b_ih,   // [200]
    const float* __restrict__ b_hh,   // [200]
    const float* __restrict__ W_out,  // [1, 50]
    const float* __restrict__ b_out,  // [1]
    float* __restrict__ out)          // [B, T]
{
    const int tid  = threadIdx.x;
    const int lane = tid & 63;
    const int wv   = tid >> 6;       // 0..7
    const int col  = lane & 15;      // A-row-in-tile / B-col(batch) / D-col(batch)
    const int quad = lane >> 4;      // k-octet / D row-group

    __shared__ __align__(16) unsigned short Hh[2][BT][HS];
    __shared__ float x_lds[BT][XS];
    __shared__ float ypart[2][NW][17];

    // zero both H buffers (k-slots 53..63 + pads must stay 0)
    for (int i = tid; i < 2 * BT * HS; i += 512)
        (&Hh[0][0][0])[i] = 0;
    // stage x[block,:,:] -> LDS (coalesced float4 reads)
    {
        const float4* xg = (const float4*)(x + (size_t)blockIdx.x * BT * TT);
        #pragma unroll
        for (int pk = 0; pk < (BT * TT / 4) / 512; ++pk) {   // 4 iters
            const int idx = pk * 512 + tid;                  // float4 index
            const float4 v = xg[idx];
            const int fb = (idx * 4) >> 9;
            const int ft = (idx * 4) & 511;
            x_lds[fb][ft + 0] = v.x; x_lds[fb][ft + 1] = v.y;
            x_lds[fb][ft + 2] = v.z; x_lds[fb][ft + 3] = v.w;
        }
    }

    // persistent A fragments: wave wv owns g^ rows [wv*32, wv*32+32) = 2 tiles
    bf16x8 Ahi[2][2], Alo[2][2];
    #pragma unroll
    for (int i = 0; i < 2; ++i) {
        const int gh  = wv * 32 + i * 16 + col;   // g^ row
        const int u   = gh >> 2;
        const int ty  = gh & 3;
        const bool vl = (u < HID);
        const int og  = ty * HID + u;             // original gate row
        #pragma unroll
        for (int kk = 0; kk < 2; ++kk) {
            #pragma unroll
            for (int j = 0; j < 8; ++j) {
                const int k = kk * 32 + quad * 8 + j;
                float v = 0.f;
                if (vl) {
                    if (k < HID)       v = W_hh[og * HID + k];
                    else if (k == 50)  v = W_ih[og];       // x_hi slot
                    else if (k == 51)  v = b_ih[og] + b_hh[og];
                    else if (k == 52)  v = W_ih[og];       // x_lo slot
                }
                const short hi = bf16_rtne(v);
                Ahi[i][kk][j] = hi;
                Alo[i][kk][j] = bf16_rtne(v - bf16_f32(hi));
            }
        }
    }

    // act-phase constants & state: lane owns units u_i = wv*8 + i*4 + quad, batch=col
    float c[2] = {0.f, 0.f};
    float wo[2];
    #pragma unroll
    for (int i = 0; i < 2; ++i) {
        const int u = wv * 8 + i * 4 + quad;
        wo[i] = (u < HID) ? W_out[u] : 0.f;
    }
    const float bo = b_out[0];
    float* yout = out + (size_t)blockIdx.x * BT * TT;

    __syncthreads();    // x_lds + zeroed H visible

    if (tid < BT) {     // bias slot (both buffers), x_0 hi/lo (buffer 0)
        Hh[0][tid][51] = 0x3F80;
        Hh[1][tid][51] = 0x3F80;
        const float x0 = x_lds[tid][0];
        const short h0 = bf16_rtne(x0);
        Hh[0][tid][50] = (unsigned short)h0;
        Hh[0][tid][52] = (unsigned short)bf16_rtne(x0 - bf16_f32(h0));
    }
    __syncthreads();

    for (int t = 0; t < TT; ++t) {
        const int p = t & 1;        // read buffer; write 1-p

        // y_{t-1}: store early so vmcnt retires under this step's compute
        if (t > 0 && tid < BT) {
            float s = bo;
            #pragma unroll
            for (int w = 0; w < NW; ++w) s += ypart[1 - p][w][tid];
            yout[(size_t)tid * TT + (t - 1)] = s;
        }

        // B fragments: B[k=kk*32+quad*8+j][n=col], single plane
        bf16x8 Bh[2];
        #pragma unroll
        for (int kk = 0; kk < 2; ++kk)
            Bh[kk] = *(const bf16x8*)&Hh[p][col][kk * 32 + quad * 8];

        float psum = 0.f;
        #pragma unroll
        for (int i = 0; i < 2; ++i) {
            f32x4 acc = {0.f, 0.f, 0.f, 0.f};
            #pragma unroll
            for (int kk = 0; kk < 2; ++kk) {
                acc = __builtin_amdgcn_mfma_f32_16x16x32_bf16(Ahi[i][kk], Bh[kk], acc, 0, 0, 0);
                acc = __builtin_amdgcn_mfma_f32_16x16x32_bf16(Alo[i][kk], Bh[kk], acc, 0, 0, 0);
            }
            // acc = {pre_i, pre_f, pre_g, pre_o} of unit u, batch col
            const int u = wv * 8 + i * 4 + quad;
            const float gi = sigmoid_fast(acc.x);
            const float gf = sigmoid_fast(acc.y);
            const float gg = tanh_fast(acc.z);
            const float go = sigmoid_fast(acc.w);
            c[i] = fmaf(gf, c[i], gi * gg);
            const float h = go * tanh_fast(c[i]);
            if (u < HID)             // don't clobber x/bias/zero k-slots
                Hh[1 - p][col][u] = (unsigned short)bf16_rtne(h);
            psum = fmaf(h, wo[i], psum);   // phantom wo = 0
        }

        // x_{t+1} hi/lo into the write buffer (conflict-free column read)
        if (tid < BT) {
            const float xn = x_lds[tid][(t + 1 < TT) ? t + 1 : t];
            const short hx = bf16_rtne(xn);
            Hh[1 - p][tid][50] = (unsigned short)hx;
            Hh[1 - p][tid][52] = (unsigned short)bf16_rtne(xn - bf16_f32(hx));
        }

        // per-wave y partial: sum over quad groups
        psum += __shfl_xor(psum, 16);
        psum += __shfl_xor(psum, 32);
        if (lane < 16) ypart[p][wv][col] = psum;

        __syncthreads();    // the ONE barrier
    }

    // epilogue: y_{TT-1}
    if (tid < BT) {
        float s = bo;
        #pragma unroll
        for (int w = 0; w < NW; ++w) s += ypart[(TT - 1) & 1][w][tid];
        yout[(size_t)tid * TT + (TT - 1)] = s;
    }
}

extern "C" void kernel_launch(void* const* d_in, const int* in_sizes, int n_in,
                              void* d_out, int out_size, void* d_ws, size_t ws_size,
                              hipStream_t stream) {
    const float* x     = (const float*)d_in[0];
    const float* W_ih  = (const float*)d_in[1];
    const float* W_hh  = (const float*)d_in[2];
    const float* b_ih  = (const float*)d_in[3];
    const float* b_hh  = (const float*)d_in[4];
    const float* W_out = (const float*)d_in[5];
    const float* b_out = (const float*)d_in[6];
    float* out = (float*)d_out;

    const int B = in_sizes[0] / TT;          // 4096
    lstm_mfma3_kernel<<<B / BT, 512, 0, stream>>>(x, W_ih, W_hh, b_ih, b_hh,
                                                  W_out, b_out, out);
}